// Round 4
// baseline (510.848 us; speedup 1.0000x reference)
//
#include <hip/hip_runtime.h>

#define N_NODES 100000
#define N_EDGES 3200000
#define IN_FEAT 512
#define HID 16
#define BNODES 128                        // nodes per bucket (dst >> 7)
#define NB 782                            // ceil(100000/128)
#define CHUNK 8192
#define NCHUNKS ((N_EDGES + CHUNK - 1) / CHUNK)   // 391

// ---------------------------------------------------------------------------
// Edge-index dtype hedge (int64 vs int32 storage), probed device-side.
// ---------------------------------------------------------------------------
__global__ void k_detect(const void* ei, int* flag) {
    const int* p = (const int*)ei;
    int t = threadIdx.x;                     // 64 threads = 1 wave
    bool nz = (p[2 * t + 1] != 0);
    unsigned long long m = __ballot(nz);
    if (t == 0) *flag = (m == 0ull) ? 1 : 0; // 1 => int64 storage
}

__device__ __forceinline__ int load_dst(const void* ei, int is64, int e) {
    if (is64) return (int)((const long long*)ei)[(long long)N_EDGES + e];
    return ((const int*)ei)[N_EDGES + e];
}
__device__ __forceinline__ int load_src(const void* ei, int is64, int e) {
    if (is64) return (int)((const long long*)ei)[e];
    return ((const int*)ei)[e];
}

// ---- bucket histogram ------------------------------------------------------
__global__ void k_hist(const void* ei, const int* __restrict__ flag,
                       int* __restrict__ ghist) {
    __shared__ int h[NB];
    int tid = threadIdx.x;
    int is64 = *flag;
    for (int i = tid; i < NB; i += 256) h[i] = 0;
    __syncthreads();
    for (int e = blockIdx.x * 256 + tid; e < N_EDGES; e += gridDim.x * 256)
        atomicAdd(&h[load_dst(ei, is64, e) >> 7], 1);
    __syncthreads();
    for (int i = tid; i < NB; i += 256)
        if (h[i]) atomicAdd(&ghist[i], h[i]);
}

// ---- exclusive scan over NB buckets (one block) ----------------------------
__global__ __launch_bounds__(1024)
void k_scan(const int* __restrict__ ghist, int* __restrict__ goff,
            int* __restrict__ gcursor) {
    __shared__ int s[1024];
    int tid = threadIdx.x;
    int v = (tid < NB) ? ghist[tid] : 0;
    s[tid] = v;
    __syncthreads();
    for (int o = 1; o < 1024; o <<= 1) {
        int t = (tid >= o) ? s[tid - o] : 0;
        __syncthreads();
        s[tid] += t;
        __syncthreads();
    }
    int excl = s[tid] - v;                 // tid==NB -> total (v==0 there)
    if (tid <= NB) goff[tid] = excl;
    if (tid < NB) gcursor[tid] = excl;
}

// ---- per-chunk LDS counting sort + coalesced bucketed scatter --------------
// entry = src<<7 | (dst & 127); bucket = dst>>7
__global__ __launch_bounds__(1024)
void k_sortscatter(const void* ei, const int* __restrict__ flag,
                   int* __restrict__ gcursor, unsigned* __restrict__ colp) {
    __shared__ unsigned sorted[CHUNK];     // 32 KB
    __shared__ int hist[1024];             // doubles as cursor
    __shared__ int scanL[1024];
    __shared__ int gbase[1024];
    int tid = threadIdx.x;
    int base = blockIdx.x * CHUNK;
    int chunkN = min(CHUNK, N_EDGES - base);
    int is64 = *flag;

    hist[tid] = 0;
    __syncthreads();

    unsigned ent[8];
    short bkt[8];
#pragma unroll
    for (int k = 0; k < 8; ++k) {
        int i = k * 1024 + tid;
        if (i < chunkN) {
            int e = base + i;
            int s = load_src(ei, is64, e);
            int d = load_dst(ei, is64, e);
            int b = d >> 7;
            ent[k] = ((unsigned)s << 7) | (unsigned)(d & 127);
            bkt[k] = (short)b;
            atomicAdd(&hist[b], 1);
        } else bkt[k] = -1;
    }
    __syncthreads();

    int v = hist[tid];
    scanL[tid] = v;
    __syncthreads();
    for (int o = 1; o < 1024; o <<= 1) {
        int t = (tid >= o) ? scanL[tid - o] : 0;
        __syncthreads();
        scanL[tid] += t;
        __syncthreads();
    }
    int excl = scanL[tid] - v;
    __syncthreads();
    scanL[tid] = excl;                     // scanL[NB] == chunkN automatically
    hist[tid] = 0;                         // reuse as within-bucket cursor
    __syncthreads();

#pragma unroll
    for (int k = 0; k < 8; ++k) {
        if (bkt[k] >= 0) {
            int b = bkt[k];
            int pos = atomicAdd(&hist[b], 1);
            sorted[scanL[b] + pos] = ent[k];
        }
    }
    __syncthreads();

    if (tid < NB) {
        int cnt = scanL[tid + 1] - scanL[tid];
        gbase[tid] = (cnt > 0) ? atomicAdd(&gcursor[tid], cnt) : 0;
    }
    __syncthreads();

    for (int i = tid; i < chunkN; i += 1024) {
        int lo = 0, hi = NB;               // invariant: scanL[lo] <= i < scanL[hi]
        while (hi - lo > 1) {
            int mid = (lo + hi) >> 1;
            if (scanL[mid] <= i) lo = mid; else hi = mid;
        }
        colp[gbase[lo] + (i - scanL[lo])] = sorted[i];
    }
}

// ---- degree (from bucketed entries) -> dinv --------------------------------
__global__ void k_degdinv(const int* __restrict__ goff,
                          const unsigned* __restrict__ colp,
                          float* __restrict__ dinv) {
    __shared__ int cnt[BNODES];
    int b = blockIdx.x, tid = threadIdx.x;
    if (tid < BNODES) cnt[tid] = 0;
    __syncthreads();
    int s0 = goff[b], s1 = goff[b + 1];
    for (int i = s0 + tid; i < s1; i += 256)
        atomicAdd(&cnt[colp[i] & 127], 1);
    __syncthreads();
    if (tid < BNODES) {
        int node = (b << 7) + tid;
        if (node < N_NODES) dinv[node] = rsqrtf((float)(cnt[tid] + 1));
    }
}

// ---- xws = (x @ W1) * dinv[row] -------------------------------------------
__global__ void k_gemm1(const float* __restrict__ x, const float* __restrict__ W1,
                        const float* __restrict__ dinv, float* __restrict__ xws) {
    int row = blockIdx.x * blockDim.x + threadIdx.x;
    if (row >= N_NODES) return;
    const float4* xr = (const float4*)(x + (size_t)row * IN_FEAT);
    float acc[16];
#pragma unroll
    for (int f = 0; f < 16; ++f) acc[f] = 0.f;

#pragma unroll 1
    for (int k0 = 0; k0 < IN_FEAT; k0 += 16) {
        float4 v0 = xr[k0 / 4 + 0];
        float4 v1 = xr[k0 / 4 + 1];
        float4 v2 = xr[k0 / 4 + 2];
        float4 v3 = xr[k0 / 4 + 3];
        float xv[16] = {v0.x, v0.y, v0.z, v0.w, v1.x, v1.y, v1.z, v1.w,
                        v2.x, v2.y, v2.z, v2.w, v3.x, v3.y, v3.z, v3.w};
#pragma unroll
        for (int kk = 0; kk < 16; ++kk) {
            const float* wr = W1 + (size_t)(k0 + kk) * HID;
#pragma unroll
            for (int f = 0; f < HID; ++f)
                acc[f] = fmaf(xv[kk], wr[f], acc[f]);
        }
    }
    float di = dinv[row];
    float4* xv4 = (float4*)(xws + (size_t)row * HID);
#pragma unroll
    for (int q = 0; q < 4; ++q)
        xv4[q] = make_float4(acc[4 * q] * di, acc[4 * q + 1] * di,
                             acc[4 * q + 2] * di, acc[4 * q + 3] * di);
}

// ---- layer-1 aggregation in LDS, 16-deep MLP unroll -----------------------
// out1 = relu(b1 + dinv*(self + sum_{src->d} xws[src]))
__global__ __launch_bounds__(512)
void k_aggr1(const int* __restrict__ goff, const unsigned* __restrict__ colp,
             const float* __restrict__ dinv, const float* __restrict__ xws,
             const float* __restrict__ b1, float* __restrict__ out1) {
    __shared__ float acc[BNODES * HID];    // 8 KB
    int b = blockIdx.x, tid = threadIdx.x;
    int f = tid & 15;
    int eg = tid >> 4;                     // 0..31 edge-slot within block
    for (int i = tid; i < BNODES * HID; i += 512) acc[i] = 0.f;
    __syncthreads();
    int s0 = goff[b], s1 = goff[b + 1];
    const int STEP = 32 * 16;              // 512 edges per outer iter
    for (int i0 = s0; i0 < s1; i0 += STEP) {
        unsigned ent[16];
        float val[16];
#pragma unroll
        for (int k = 0; k < 16; ++k) {
            int idx = i0 + k * 32 + eg;
            ent[k] = (idx < s1) ? colp[idx] : 0xFFFFFFFFu;
        }
#pragma unroll
        for (int k = 0; k < 16; ++k)
            val[k] = (ent[k] != 0xFFFFFFFFu)
                     ? xws[(size_t)(ent[k] >> 7) * HID + f] : 0.f;
#pragma unroll
        for (int k = 0; k < 16; ++k)
            if (ent[k] != 0xFFFFFFFFu)
                atomicAdd(&acc[(int)(ent[k] & 127u) * HID + f], val[k]);
    }
    __syncthreads();
    float bias = b1[f];
    for (int r0 = 0; r0 < BNODES; r0 += 32) {
        int r = r0 + eg;
        int node = (b << 7) + r;
        if (node < N_NODES) {
            float v = fmaf(dinv[node], acc[r * HID + f] + xws[(size_t)node * HID + f], bias);
            out1[(size_t)node * HID + f] = fmaxf(v, 0.f);
        }
    }
}

// ---- h2s = (out1 @ W2) * dinv ---------------------------------------------
__global__ void k_layer2(const float* __restrict__ out1, const float* __restrict__ W2,
                         const float* __restrict__ dinv, float* __restrict__ h2s) {
    int i = blockIdx.x * blockDim.x + threadIdx.x;
    if (i >= N_NODES) return;
    const float4* hv = (const float4*)(out1 + (size_t)i * HID);
    float g0 = 0.f, g1 = 0.f;
#pragma unroll
    for (int q = 0; q < 4; ++q) {
        float4 v = hv[q];
        g0 = fmaf(v.x, W2[(4 * q + 0) * 2 + 0], g0);
        g1 = fmaf(v.x, W2[(4 * q + 0) * 2 + 1], g1);
        g0 = fmaf(v.y, W2[(4 * q + 1) * 2 + 0], g0);
        g1 = fmaf(v.y, W2[(4 * q + 1) * 2 + 1], g1);
        g0 = fmaf(v.z, W2[(4 * q + 2) * 2 + 0], g0);
        g1 = fmaf(v.z, W2[(4 * q + 2) * 2 + 1], g1);
        g0 = fmaf(v.w, W2[(4 * q + 3) * 2 + 0], g0);
        g1 = fmaf(v.w, W2[(4 * q + 3) * 2 + 1], g1);
    }
    float di = dinv[i];
    ((float2*)h2s)[i] = make_float2(g0 * di, g1 * di);
}

// ---- layer-2 aggregation + log_softmax, 8-deep MLP unroll -----------------
__global__ __launch_bounds__(512)
void k_aggr2(const int* __restrict__ goff, const unsigned* __restrict__ colp,
             const float* __restrict__ dinv, const float* __restrict__ h2s,
             const float* __restrict__ b2, float* __restrict__ y) {
    __shared__ float acc[BNODES * 2];
    int b = blockIdx.x, tid = threadIdx.x;
    int c = tid & 1;
    int eg = tid >> 1;                     // 0..255
    for (int i = tid; i < BNODES * 2; i += 512) acc[i] = 0.f;
    __syncthreads();
    int s0 = goff[b], s1 = goff[b + 1];
    const int STEP = 256 * 8;              // 2048 edges per outer iter
    for (int i0 = s0; i0 < s1; i0 += STEP) {
        unsigned ent[8];
        float val[8];
#pragma unroll
        for (int k = 0; k < 8; ++k) {
            int idx = i0 + k * 256 + eg;
            ent[k] = (idx < s1) ? colp[idx] : 0xFFFFFFFFu;
        }
#pragma unroll
        for (int k = 0; k < 8; ++k)
            val[k] = (ent[k] != 0xFFFFFFFFu)
                     ? h2s[(size_t)(ent[k] >> 7) * 2 + c] : 0.f;
#pragma unroll
        for (int k = 0; k < 8; ++k)
            if (ent[k] != 0xFFFFFFFFu)
                atomicAdd(&acc[(int)(ent[k] & 127u) * 2 + c], val[k]);
    }
    __syncthreads();
    if (tid < BNODES * 2) {
        int r = tid >> 1;
        int node = (b << 7) + r;
        if (node < N_NODES) {
            float v = fmaf(dinv[node], acc[tid] + h2s[(size_t)node * 2 + c], b2[c]);
            float o = __shfl_xor(v, 1);
            float m = fmaxf(v, o);
            float lse = m + logf(expf(v - m) + expf(o - m));
            y[(size_t)node * 2 + c] = v - lse;
        }
    }
}

extern "C" void kernel_launch(void* const* d_in, const int* in_sizes, int n_in,
                              void* d_out, int out_size, void* d_ws, size_t ws_size,
                              hipStream_t stream) {
    const float* x  = (const float*)d_in[0];
    const void*  ei = d_in[1];
    const float* W1 = (const float*)d_in[2];
    const float* b1 = (const float*)d_in[3];
    const float* W2 = (const float*)d_in[4];
    const float* b2 = (const float*)d_in[5];
    float* y = (float*)d_out;

    char* w = (char*)d_ws;
    int*      flag    = (int*)(w + 0);
    int*      ghist   = (int*)(w + 1024);       // 3128 B
    int*      goff    = (int*)(w + 8192);       // 3132 B
    int*      gcursor = (int*)(w + 16384);      // 3128 B
    float*    dinv    = (float*)(w + 24576);    // 400 KB
    unsigned* colp    = (unsigned*)(w + 425984);    // 12.8 MB
    float*    xws     = (float*)(w + 13230080);     // 6.4 MB
    float*    out1    = (float*)(w + 19631104);     // 6.4 MB
    float*    h2s     = (float*)(w + 26032128);     // 800 KB -> ends ~26.8 MB

    hipMemsetAsync(ghist, 0, NB * sizeof(int), stream);
    k_detect<<<1, 64, 0, stream>>>(ei, flag);
    k_hist<<<512, 256, 0, stream>>>(ei, flag, ghist);
    k_scan<<<1, 1024, 0, stream>>>(ghist, goff, gcursor);
    k_sortscatter<<<NCHUNKS, 1024, 0, stream>>>(ei, flag, gcursor, colp);
    k_degdinv<<<NB, 256, 0, stream>>>(goff, colp, dinv);
    k_gemm1<<<(N_NODES + 255) / 256, 256, 0, stream>>>(x, W1, dinv, xws);
    k_aggr1<<<NB, 512, 0, stream>>>(goff, colp, dinv, xws, b1, out1);
    k_layer2<<<(N_NODES + 255) / 256, 256, 0, stream>>>(out1, W2, dinv, h2s);
    k_aggr2<<<NB, 512, 0, stream>>>(goff, colp, dinv, h2s, b2, y);
}